// Round 5
// baseline (141.852 us; speedup 1.0000x reference)
//
#include <hip/hip_runtime.h>
#include <hip/hip_bf16.h>

// Problem constants (fixed by reference):
//   B=16, L=512, D=C=F=256, K=3, M=2048, EPS=1e-5
// Float tensors f32; target int32. Convs on bf16 MFMA (f32 accum).
#define Bn 16
#define Ln 512
#define Cn 256
#define Fn 256
#define Kn 3
#define Mn 2048

#define NKSTEP 24        // 768 / 32
#define MT 64            // L-rows per conv block -> 128 conv blocks, 8 waves each
#define XS_PS 264        // LDS A-slab row stride (bf16 units); 528 B = 33*16
#define NCONV 128
#define NGATH 1024       // gather blocks: 32 rows x 64 float4 each
#define NPACK 384        // 196608 / 512 pack blocks per weight

typedef __attribute__((ext_vector_type(8))) short short8;
typedef __attribute__((ext_vector_type(4))) float f32x4;

static __device__ __forceinline__ unsigned short f2bf(float f) {
    unsigned int u = __float_as_uint(f);
    return (unsigned short)((u + 0x7fff + ((u >> 16) & 1)) >> 16);   // RNE
}

// pack element i of w (F,C,K) f32 into MFMA B-frag order (verified r3/r4):
// bp[((s*16+nt)*64+lane)*8+j] = w[f=nt*16+(lane&15)][d][k], kappa=k*256+d=s*32+(lane>>4)*8+j
static __device__ __forceinline__ void pack_one(const float* __restrict__ w,
                                                unsigned short* __restrict__ bp,
                                                int i) {
    int j    = i & 7;
    int lane = (i >> 3) & 63;
    int nt   = (i >> 9) & 15;
    int s    = i >> 13;
    int kap = s * 32 + ((lane >> 4) * 8) + j;
    int k = kap >> 8;
    int d = kap & 255;
    int f = nt * 16 + (lane & 15);
    bp[i] = f2bf(w[(f * Cn + d) * Kn + k]);
}

// ---------- K1: pack w1 (blocks 0..383) + duration scan (blocks 384..399) ----------
__global__ __launch_bounds__(512) void pack_scan(
    const float* __restrict__ w1, unsigned short* __restrict__ bp1,
    const int* __restrict__ target, int* __restrict__ map)
{
    __shared__ int ss[Ln];
    const int blk = blockIdx.x;
    const int t = threadIdx.x;
    if (blk < NPACK) { pack_one(w1, bp1, blk * 512 + t); return; }
    int b = blk - NPACK;
    int v = target[b * Ln + t];
    ss[t] = v;
    __syncthreads();
    for (int off = 1; off < Ln; off <<= 1) {
        int add = (t >= off) ? ss[t - off] : 0;
        __syncthreads();
        ss[t] += add;
        __syncthreads();
    }
    int cs    = ss[t];          // inclusive cumsum
    int prev  = cs - v;
    int total = ss[Ln - 1];
    for (int m = prev; m < cs; ++m) map[b * Mn + m] = t;
    for (int m = total + t; m < Mn; m += Ln) map[b * Mn + m] = -1;
}

// ---------- fused conv1d(K=3,SAME) via MFMA + bias + LayerNorm + ReLU ----------
// Conv blocks [0,128): 64 L-rows of one batch; 8 waves; wave wv owns n-tiles
// {2wv,2wv+1} (each B-frag read ONCE per block) and all 4 m-tiles.
// A-frag (16x16x32): A[m=lane&15][k=(lane>>4)*8+j]; C/D: col=lane&15, row=(lane>>4)*4+reg.
// WITH_AUX (K2 only): blocks [128,1152) = length-regulate gather; [1152,1536) = pack w2.
template <bool IS_F32_IN, bool DO_LINEAR, bool WITH_AUX>
__global__ __launch_bounds__(512) void conv_mfma(
    const void* __restrict__ in_,               // (B,L,C) f32 or bf16
    const unsigned short* __restrict__ bp,      // packed weights (bf16 frag order)
    const float* __restrict__ bias,             // (F)
    const float* __restrict__ gamma,            // (F)
    const float* __restrict__ beta,             // (F)
    const float* __restrict__ lw,               // (F)  [DO_LINEAR]
    const float* __restrict__ lb,               // (1)  [DO_LINEAR]
    unsigned short* __restrict__ hout,          // bf16 (B,L,F) [!DO_LINEAR]
    float* __restrict__ dup,                    // (B,L)        [DO_LINEAR]
    const float* __restrict__ gx,               // (B,L,C) f32  [WITH_AUX]
    const int* __restrict__ gmap,               // (B,M)        [WITH_AUX]
    float* __restrict__ gout,                   // (B,M,C)      [WITH_AUX]
    const float* __restrict__ wsrc,             // w2 (F,C,K)   [WITH_AUX]
    unsigned short* __restrict__ bpdst)         // bp2          [WITH_AUX]
{
    __shared__ __align__(16) unsigned short xs[(MT + 2) * XS_PS];  // ~34.8 KB
    __shared__ float2 red[MT][8];                                  // 4 KB
    __shared__ float  red2[MT][8];                                 // 2 KB

    const int t = threadIdx.x;

    if (WITH_AUX && blockIdx.x >= NCONV) {
        int rel = blockIdx.x - NCONV;
        if (rel < NGATH) {
            // ---- length-regulate gather: 32 rows/block, 16 threads per row ----
            int bm = rel * 32 + (t >> 4);
            int l  = gmap[bm];
            int b  = bm >> 11;
            int lc = (l >= 0) ? l : 0;
            const float4* src = (const float4*)(gx + ((size_t)b * Ln + lc) * Cn) + (t & 15);
            float4* dst = (float4*)gout + (size_t)bm * 64 + (t & 15);
            float4 z = make_float4(0.f, 0.f, 0.f, 0.f);
            #pragma unroll
            for (int j = 0; j < 4; ++j)
                dst[j * 16] = (l >= 0) ? src[j * 16] : z;
        } else {
            // ---- pack w2 -> bp2 (consumed by the NEXT kernel) ----
            pack_one(wsrc, bpdst, (rel - NGATH) * 512 + t);
        }
        return;
    }

    const int b  = blockIdx.x >> 3;          // 8 l-tiles per batch
    const int l0 = (blockIdx.x & 7) * MT;

    // ---- stage input rows [l0-1, l0+64], zero-padded, as bf16 ----
    if (IS_F32_IN) {
        const float* in = (const float*)in_;
        for (int idx = t; idx < (MT + 2) * 64; idx += 512) {   // 64 float4 per row
            int row = idx >> 6;
            int c4  = (idx & 63) * 4;
            int l = l0 + row - 1;
            float4 v = make_float4(0.f, 0.f, 0.f, 0.f);
            if (l >= 0 && l < Ln) v = *(const float4*)&in[((size_t)b * Ln + l) * Cn + c4];
            unsigned int lo = (unsigned int)f2bf(v.x) | ((unsigned int)f2bf(v.y) << 16);
            unsigned int hi = (unsigned int)f2bf(v.z) | ((unsigned int)f2bf(v.w) << 16);
            *(uint2*)&xs[row * XS_PS + c4] = make_uint2(lo, hi);
        }
    } else {
        const unsigned short* in = (const unsigned short*)in_;
        for (int idx = t; idx < (MT + 2) * 32; idx += 512) {   // 32 x (8 bf16) per row
            int row = idx >> 5;
            int c8  = (idx & 31) * 8;
            int l = l0 + row - 1;
            uint4 v = make_uint4(0u, 0u, 0u, 0u);
            if (l >= 0 && l < Ln) v = *(const uint4*)&in[((size_t)b * Ln + l) * Cn + c8];
            *(uint4*)&xs[row * XS_PS + c8] = v;
        }
    }
    __syncthreads();

    const int lane = t & 63;
    const int wv   = t >> 6;      // n-group: cols wv*32 .. wv*32+31
    const int mrow = lane & 15;
    const int q    = lane >> 4;

    f32x4  acc[4][2] = {};
    short8 bfr[3][2];             // 3-slot rings, loaded 3 steps ahead
    short8 afr[3][4];

    auto loadB = [&](int s, int slot) {
        const unsigned short* p = bp + (size_t)((s * 16 + wv * 2) * 64 + lane) * 8;
        bfr[slot][0] = *(const short8*)p;
        bfr[slot][1] = *(const short8*)(p + 512);
    };
    auto loadA = [&](int s, int slot) {
        const int k    = s >> 3;
        const int dcol = (s & 7) * 32 + q * 8;
        #pragma unroll
        for (int mt = 0; mt < 4; ++mt)
            afr[slot][mt] = *(const short8*)&xs[(mt * 16 + mrow + k) * XS_PS + dcol];
    };

    loadB(0, 0); loadA(0, 0);
    loadB(1, 1); loadA(1, 1);
    loadB(2, 2); loadA(2, 2);

    #pragma unroll
    for (int s = 0; s < NKSTEP; ++s) {
        const int slot = s % 3;
        #pragma unroll
        for (int mt = 0; mt < 4; ++mt)
            #pragma unroll
            for (int i = 0; i < 2; ++i)
                acc[mt][i] = __builtin_amdgcn_mfma_f32_16x16x32_bf16(
                    afr[slot][mt], bfr[slot][i], acc[mt][i], 0, 0, 0);
        if (s + 3 < NKSTEP) { loadB(s + 3, slot); loadA(s + 3, slot); }
    }

    // ---- epilogue: bias + LayerNorm from registers ----
    float biasv[2], gv[2], bv[2], lwv[2];
    #pragma unroll
    for (int i = 0; i < 2; ++i) {
        int col = wv * 32 + i * 16 + mrow;
        biasv[i] = bias[col];
        gv[i]    = gamma[col];
        bv[i]    = beta[col];
        if (DO_LINEAR) lwv[i] = lw[col];
    }
    #pragma unroll
    for (int mt = 0; mt < 4; ++mt)
        #pragma unroll
        for (int i = 0; i < 2; ++i)
            #pragma unroll
            for (int r = 0; r < 4; ++r)
                acc[mt][i][r] += biasv[i];

    // per-row partials over this wave's 32 cols: in-lane over i, shuffle over mrow lanes
    #pragma unroll
    for (int mt = 0; mt < 4; ++mt)
        #pragma unroll
        for (int r = 0; r < 4; ++r) {
            float s  = acc[mt][0][r] + acc[mt][1][r];
            float sq = acc[mt][0][r] * acc[mt][0][r] + acc[mt][1][r] * acc[mt][1][r];
            #pragma unroll
            for (int off = 1; off <= 8; off <<= 1) {
                s  += __shfl_xor(s,  off, 64);
                sq += __shfl_xor(sq, off, 64);
            }
            if (mrow == 0) red[mt * 16 + q * 4 + r][wv] = make_float2(s, sq);
        }
    __syncthreads();

    float muv[4][4], rsv[4][4];
    #pragma unroll
    for (int mt = 0; mt < 4; ++mt)
        #pragma unroll
        for (int r = 0; r < 4; ++r) {
            int row = mt * 16 + q * 4 + r;
            float s = 0.f, sq = 0.f;
            #pragma unroll
            for (int w = 0; w < 8; ++w) {
                float2 p = red[row][w];
                s += p.x; sq += p.y;
            }
            float mu  = s * (1.f / 256.f);
            float var = sq * (1.f / 256.f) - mu * mu;
            muv[mt][r] = mu;
            rsv[mt][r] = rsqrtf(var + 1e-5f);
        }

    if (!DO_LINEAR) {
        // store relu(LN(h)) as bf16
        #pragma unroll
        for (int mt = 0; mt < 4; ++mt)
            #pragma unroll
            for (int r = 0; r < 4; ++r) {
                int l = l0 + mt * 16 + q * 4 + r;
                size_t base = ((size_t)b * Ln + l) * Fn;
                #pragma unroll
                for (int i = 0; i < 2; ++i) {
                    float o = fmaxf((acc[mt][i][r] - muv[mt][r]) * rsv[mt][r] * gv[i] + bv[i], 0.f);
                    hout[base + wv * 32 + i * 16 + mrow] = f2bf(o);
                }
            }
    } else {
        // fused linear head: dup = relu( relu(LN(h)) . lw + lb )
        #pragma unroll
        for (int mt = 0; mt < 4; ++mt)
            #pragma unroll
            for (int r = 0; r < 4; ++r) {
                float dot = 0.f;
                #pragma unroll
                for (int i = 0; i < 2; ++i) {
                    float o = fmaxf((acc[mt][i][r] - muv[mt][r]) * rsv[mt][r] * gv[i] + bv[i], 0.f);
                    dot += o * lwv[i];
                }
                #pragma unroll
                for (int off = 1; off <= 8; off <<= 1)
                    dot += __shfl_xor(dot, off, 64);
                if (mrow == 0) red2[mt * 16 + q * 4 + r][wv] = dot;
            }
        __syncthreads();
        if (t < MT) {
            float d = 0.f;
            #pragma unroll
            for (int w = 0; w < 8; ++w) d += red2[t][w];
            dup[b * Ln + l0 + t] = fmaxf(d + lb[0], 0.f);
        }
    }
}

extern "C" void kernel_launch(void* const* d_in, const int* in_sizes, int n_in,
                              void* d_out, int out_size, void* d_ws, size_t ws_size,
                              hipStream_t stream) {
    const float* x    = (const float*)d_in[0];
    const int*   targ = (const int*)d_in[1];
    // d_in[2] = mel_max_length (scalar) = 2048, hardcoded
    const float* c1w = (const float*)d_in[3];
    const float* c1b = (const float*)d_in[4];
    const float* g1  = (const float*)d_in[5];
    const float* be1 = (const float*)d_in[6];
    const float* c2w = (const float*)d_in[7];
    const float* c2b = (const float*)d_in[8];
    const float* g2  = (const float*)d_in[9];
    const float* be2 = (const float*)d_in[10];
    const float* lw  = (const float*)d_in[11];
    const float* lb  = (const float*)d_in[12];

    float* out     = (float*)d_out;                       // (B,M,C)
    float* out_dup = out + (size_t)Bn * Mn * Cn;          // (B,L)

    // workspace layout
    char* ws = (char*)d_ws;
    unsigned short* bp1 = (unsigned short*)ws;                       // 384 KiB
    unsigned short* bp2 = (unsigned short*)(ws + 393216);            // 384 KiB
    unsigned short* h1  = (unsigned short*)(ws + 2 * 393216);        // 4 MiB bf16
    int*            map = (int*)(ws + 2 * 393216 + 4194304);         // 128 KiB

    // K1: pack w1 (384 blocks) + duration scan (16 blocks)
    pack_scan<<<NPACK + Bn, 512, 0, stream>>>(c1w, bp1, targ, map);

    // K2: conv1 [0,128) + gather [128,1152) + pack w2 [1152,1536)
    conv_mfma<true, false, true><<<NCONV + NGATH + NPACK, 512, 0, stream>>>(
        (const void*)x, bp1, c1b, g1, be1, nullptr, nullptr, h1, nullptr,
        x, map, out, c2w, bp2);

    // K3: conv2 + fused linear head -> dup
    conv_mfma<false, true, false><<<NCONV, 512, 0, stream>>>(
        (const void*)h1, bp2, c2b, g2, be2, lw, lb, nullptr, out_dup,
        nullptr, nullptr, nullptr, nullptr, nullptr);
}

// Round 6
// 117.981 us; speedup vs baseline: 1.2023x; 1.2023x over previous
//
#include <hip/hip_runtime.h>
#include <hip/hip_bf16.h>

// Problem constants (fixed by reference):
//   B=16, L=512, D=C=F=256, K=3, M=2048, EPS=1e-5
// Float tensors f32; target int32. Convs on bf16 MFMA (f32 accum).
#define Bn 16
#define Ln 512
#define Cn 256
#define Fn 256
#define Kn 3
#define Mn 2048

#define NKSTEP 24        // 768 / 32
#define MT 32            // L-rows per conv block -> grid 256 (1 block/CU)
#define XS_PS 264        // LDS A-slab row stride (bf16 units); 528 B = 33*16
#define NCONVBLK 256
#define NGATH_HALF 4096  // gather float4-blocks per conv kernel (2 x 4096 x 256 = 2097152 total)

typedef __attribute__((ext_vector_type(8))) short short8;
typedef __attribute__((ext_vector_type(4))) float f32x4;

static __device__ __forceinline__ unsigned short f2bf(float f) {
    unsigned int u = __float_as_uint(f);
    return (unsigned short)((u + 0x7fff + ((u >> 16) & 1)) >> 16);   // RNE
}

// ---------- K1: pack both conv weights into MFMA B-frag order + duration scan ----------
// blocks 0..1535: pack. bp[((s*16+nt)*64+lane)*8+j] = w[f=nt*16+(lane&15)][d][k],
//                 kappa = k*256+d = s*32 + (lane>>4)*8 + j.   (layout verified r3/r4)
// blocks 1536..1551: per-batch cumsum of target -> m->l map (-1 = zero-fill).
__global__ __launch_bounds__(256) void pack_scan(
    const float* __restrict__ w1, const float* __restrict__ w2,
    unsigned short* __restrict__ bp1, unsigned short* __restrict__ bp2,
    const int* __restrict__ target, int* __restrict__ map)
{
    __shared__ int ss[256];
    const int blk = blockIdx.x;
    const int t = threadIdx.x;
    if (blk < 1536) {
        int i = blk * 256 + t;
        const float* w = w1;
        unsigned short* bp = bp1;
        if (i >= Fn * Cn * Kn) { i -= Fn * Cn * Kn; w = w2; bp = bp2; }
        int j    = i & 7;
        int lane = (i >> 3) & 63;
        int nt   = (i >> 9) & 15;
        int s    = i >> 13;
        int kap = s * 32 + ((lane >> 4) * 8) + j;
        int k = kap >> 8;
        int d = kap & 255;
        int f = nt * 16 + (lane & 15);
        bp[i] = f2bf(w[(f * Cn + d) * Kn + k]);
    } else {
        int b = blk - 1536;
        int v0 = target[b * Ln + 2 * t];
        int v1 = target[b * Ln + 2 * t + 1];
        ss[t] = v0 + v1;
        __syncthreads();
        for (int off = 1; off < 256; off <<= 1) {
            int add = (t >= off) ? ss[t - off] : 0;
            __syncthreads();
            ss[t] += add;
            __syncthreads();
        }
        int S     = ss[t];        // inclusive pair-scan -> cumsum at 2t+1
        int total = ss[255];
        int cs1   = S;
        int cs0   = S - v1;
        int prev0 = cs0 - v0;
        for (int m = prev0; m < cs0; ++m) map[b * Mn + m] = 2 * t;
        for (int m = cs0;   m < cs1; ++m) map[b * Mn + m] = 2 * t + 1;
        for (int m = total + t; m < Mn; m += 256) map[b * Mn + m] = -1;
    }
}

// ---------- fused conv1d(K=3,SAME) via MFMA + bias + LayerNorm + ReLU ----------
// Conv blocks (0..255): 32 L-rows of one batch; 4 waves, wave = 2 m-tiles x 4 n-tiles.
// A-frag (16x16x32): A[m=lane&15][k=(lane>>4)*8+j]; C/D: col=lane&15, row=(lane>>4)*4+reg.
// LN done in register space from the accumulator (no big LDS round-trip).
// WITH_AUX: blocks >= 256 do a slice of the length-regulate gather (independent work
// co-resident with the conv -> latency hiding for BOTH conv kernels).
template <bool IS_F32_IN, bool DO_LINEAR, bool WITH_AUX>
__global__ __launch_bounds__(256) void conv_mfma(
    const void* __restrict__ in_,               // (B,L,C) f32 or bf16
    const unsigned short* __restrict__ bp,      // packed weights (bf16 frag order)
    const float* __restrict__ bias,             // (F)
    const float* __restrict__ gamma,            // (F)
    const float* __restrict__ beta,             // (F)
    const float* __restrict__ lw,               // (F)  [DO_LINEAR]
    const float* __restrict__ lb,               // (1)  [DO_LINEAR]
    unsigned short* __restrict__ hout,          // bf16 (B,L,F) [!DO_LINEAR]
    float* __restrict__ dup,                    // (B,L)        [DO_LINEAR]
    const float* __restrict__ gx,               // (B,L,C) f32  [WITH_AUX]
    const int* __restrict__ gmap,               // (B,M)        [WITH_AUX]
    float* __restrict__ gout,                   // (B,M,C)      [WITH_AUX]
    int gofs)                                   // gather e4 offset [WITH_AUX]
{
    __shared__ __align__(16) unsigned short xs[(MT + 2) * XS_PS];  // ~18 KB
    __shared__ float2 red[MT][4];                                  // 1 KB
    __shared__ float  red2[MT][4];                                 // 0.5 KB

    const int t = threadIdx.x;

    if (WITH_AUX && blockIdx.x >= NCONVBLK) {
        // ---- length-regulate gather slice: out[b,m,:] = (map>=0) ? x[b,map,:] : 0 ----
        int e4 = (blockIdx.x - NCONVBLK) * 256 + t + gofs;   // float4 index
        int d4 = e4 & 63;
        int bm = e4 >> 6;
        int b  = bm >> 11;
        int l  = gmap[bm];
        float4 val = make_float4(0.f, 0.f, 0.f, 0.f);
        if (l >= 0) val = *((const float4*)(gx + (size_t)(b * Ln + l) * Cn) + d4);
        ((float4*)gout)[e4] = val;
        return;
    }

    const int b  = blockIdx.x >> 4;          // 16 l-tiles per batch
    const int l0 = (blockIdx.x & 15) * MT;

    // ---- stage input rows [l0-1, l0+32], zero-padded, as bf16 ----
    if (IS_F32_IN) {
        const float* in = (const float*)in_;
        for (int idx = t; idx < (MT + 2) * 64; idx += 256) {   // 64 float4 per row
            int row = idx >> 6;
            int c4  = (idx & 63) * 4;
            int l = l0 + row - 1;
            float4 v = make_float4(0.f, 0.f, 0.f, 0.f);
            if (l >= 0 && l < Ln) v = *(const float4*)&in[((size_t)b * Ln + l) * Cn + c4];
            unsigned int lo = (unsigned int)f2bf(v.x) | ((unsigned int)f2bf(v.y) << 16);
            unsigned int hi = (unsigned int)f2bf(v.z) | ((unsigned int)f2bf(v.w) << 16);
            *(uint2*)&xs[row * XS_PS + c4] = make_uint2(lo, hi);
        }
    } else {
        const unsigned short* in = (const unsigned short*)in_;
        for (int idx = t; idx < (MT + 2) * 32; idx += 256) {   // 32 x (8 bf16) per row
            int row = idx >> 5;
            int c8  = (idx & 31) * 8;
            int l = l0 + row - 1;
            uint4 v = make_uint4(0u, 0u, 0u, 0u);
            if (l >= 0 && l < Ln) v = *(const uint4*)&in[((size_t)b * Ln + l) * Cn + c8];
            *(uint4*)&xs[row * XS_PS + c8] = v;
        }
    }
    __syncthreads();

    const int lane = t & 63;
    const int wv   = t >> 6;      // n-group: cols wv*64 .. wv*64+63
    const int mrow = lane & 15;
    const int q    = lane >> 4;

    f32x4  acc[2][4] = {};
    short8 bfr[2][4];             // 2-slot ring, loaded 2 steps ahead
    short8 afr[2][2];

    auto loadB = [&](int s, int slot) {
        const unsigned short* p = bp + (size_t)((s * 16 + wv * 4) * 64 + lane) * 8;
        #pragma unroll
        for (int i = 0; i < 4; ++i)
            bfr[slot][i] = *(const short8*)(p + (size_t)i * 64 * 8);
    };
    auto loadA = [&](int s, int slot) {
        const int k    = s >> 3;
        const int dcol = (s & 7) * 32 + q * 8;
        #pragma unroll
        for (int mt = 0; mt < 2; ++mt)
            afr[slot][mt] = *(const short8*)&xs[(mt * 16 + mrow + k) * XS_PS + dcol];
    };

    loadB(0, 0); loadA(0, 0);
    loadB(1, 1); loadA(1, 1);

    #pragma unroll 2
    for (int s = 0; s < NKSTEP; ++s) {
        const int slot = s & 1;
        #pragma unroll
        for (int mt = 0; mt < 2; ++mt)
            #pragma unroll
            for (int i = 0; i < 4; ++i)
                acc[mt][i] = __builtin_amdgcn_mfma_f32_16x16x32_bf16(
                    afr[slot][mt], bfr[slot][i], acc[mt][i], 0, 0, 0);
        const int sn = (s + 2 < NKSTEP) ? (s + 2) : s;   // tail: harmless reload
        loadB(sn, slot);
        loadA(sn, slot);
    }

    // ---- epilogue: bias + LayerNorm from registers ----
    float gv[4], bv[4], lwv[4], biasv[4];
    #pragma unroll
    for (int i = 0; i < 4; ++i) {
        int col = wv * 64 + i * 16 + mrow;
        biasv[i] = bias[col];
        gv[i]    = gamma[col];
        bv[i]    = beta[col];
        if (DO_LINEAR) lwv[i] = lw[col];
    }
    #pragma unroll
    for (int mt = 0; mt < 2; ++mt)
        #pragma unroll
        for (int i = 0; i < 4; ++i)
            #pragma unroll
            for (int r = 0; r < 4; ++r)
                acc[mt][i][r] += biasv[i];

    // per-row partials over this wave's 64 cols: in-lane over i, shuffle over mrow lanes
    #pragma unroll
    for (int mt = 0; mt < 2; ++mt)
        #pragma unroll
        for (int r = 0; r < 4; ++r) {
            float s  = acc[mt][0][r] + acc[mt][1][r] + acc[mt][2][r] + acc[mt][3][r];
            float sq = acc[mt][0][r] * acc[mt][0][r] + acc[mt][1][r] * acc[mt][1][r]
                     + acc[mt][2][r] * acc[mt][2][r] + acc[mt][3][r] * acc[mt][3][r];
            #pragma unroll
            for (int off = 1; off <= 8; off <<= 1) {
                s  += __shfl_xor(s,  off, 64);
                sq += __shfl_xor(sq, off, 64);
            }
            if (mrow == 0) red[mt * 16 + q * 4 + r][wv] = make_float2(s, sq);
        }
    __syncthreads();

    float muv[2][4], rsv[2][4];
    #pragma unroll
    for (int mt = 0; mt < 2; ++mt)
        #pragma unroll
        for (int r = 0; r < 4; ++r) {
            int row = mt * 16 + q * 4 + r;
            float2 p0 = red[row][0], p1 = red[row][1], p2 = red[row][2], p3 = red[row][3];
            float s  = p0.x + p1.x + p2.x + p3.x;
            float sq = p0.y + p1.y + p2.y + p3.y;
            float mu  = s * (1.f / 256.f);
            float var = sq * (1.f / 256.f) - mu * mu;
            muv[mt][r] = mu;
            rsv[mt][r] = rsqrtf(var + 1e-5f);
        }

    if (!DO_LINEAR) {
        // store relu(LN(h)) as bf16
        #pragma unroll
        for (int mt = 0; mt < 2; ++mt)
            #pragma unroll
            for (int r = 0; r < 4; ++r) {
                int l = l0 + mt * 16 + q * 4 + r;
                size_t base = ((size_t)b * Ln + l) * Fn;
                #pragma unroll
                for (int i = 0; i < 4; ++i) {
                    float o = fmaxf((acc[mt][i][r] - muv[mt][r]) * rsv[mt][r] * gv[i] + bv[i], 0.f);
                    hout[base + wv * 64 + i * 16 + mrow] = f2bf(o);
                }
            }
    } else {
        // fused linear head: dup = relu( relu(LN(h)) . lw + lb )
        #pragma unroll
        for (int mt = 0; mt < 2; ++mt)
            #pragma unroll
            for (int r = 0; r < 4; ++r) {
                float dot = 0.f;
                #pragma unroll
                for (int i = 0; i < 4; ++i) {
                    float o = fmaxf((acc[mt][i][r] - muv[mt][r]) * rsv[mt][r] * gv[i] + bv[i], 0.f);
                    dot += o * lwv[i];
                }
                #pragma unroll
                for (int off = 1; off <= 8; off <<= 1)
                    dot += __shfl_xor(dot, off, 64);
                if (mrow == 0) red2[mt * 16 + q * 4 + r][wv] = dot;
            }
        __syncthreads();
        if (t < MT) {
            float d = red2[t][0] + red2[t][1] + red2[t][2] + red2[t][3];
            dup[b * Ln + l0 + t] = fmaxf(d + lb[0], 0.f);
        }
    }
}

extern "C" void kernel_launch(void* const* d_in, const int* in_sizes, int n_in,
                              void* d_out, int out_size, void* d_ws, size_t ws_size,
                              hipStream_t stream) {
    const float* x    = (const float*)d_in[0];
    const int*   targ = (const int*)d_in[1];
    // d_in[2] = mel_max_length (scalar) = 2048, hardcoded
    const float* c1w = (const float*)d_in[3];
    const float* c1b = (const float*)d_in[4];
    const float* g1  = (const float*)d_in[5];
    const float* be1 = (const float*)d_in[6];
    const float* c2w = (const float*)d_in[7];
    const float* c2b = (const float*)d_in[8];
    const float* g2  = (const float*)d_in[9];
    const float* be2 = (const float*)d_in[10];
    const float* lw  = (const float*)d_in[11];
    const float* lb  = (const float*)d_in[12];

    float* out     = (float*)d_out;                       // (B,M,C)
    float* out_dup = out + (size_t)Bn * Mn * Cn;          // (B,L)

    // workspace layout
    char* ws = (char*)d_ws;
    unsigned short* bp1 = (unsigned short*)ws;                       // 384 KiB
    unsigned short* bp2 = (unsigned short*)(ws + 393216);            // 384 KiB
    unsigned short* h1  = (unsigned short*)(ws + 2 * 393216);        // 4 MiB bf16
    int*            map = (int*)(ws + 2 * 393216 + 4194304);         // 128 KiB

    // K1: weight pack (1536 blocks) + duration scan (16 blocks)
    pack_scan<<<1552, 256, 0, stream>>>(c1w, c2w, bp1, bp2, targ, map);

    // K2: conv1 (blocks 0..255) + gather first half (blocks 256..4351)
    conv_mfma<true, false, true><<<NCONVBLK + NGATH_HALF, 256, 0, stream>>>(
        (const void*)x, bp1, c1b, g1, be1, nullptr, nullptr, h1, nullptr,
        x, map, out, 0);

    // K3: conv2 + fused linear head (blocks 0..255) + gather second half
    conv_mfma<false, true, true><<<NCONVBLK + NGATH_HALF, 256, 0, stream>>>(
        (const void*)h1, bp2, c2b, g2, be2, lw, lb, nullptr, out_dup,
        x, map, out, NGATH_HALF * 256);
}